// Round 7
// baseline (172.442 us; speedup 1.0000x reference)
//
#include <hip/hip_runtime.h>
#include <math.h>

#define H 512
#define W 512
#define NPIX (32LL*512*512)

// vch LDS: [6 ch][4 rows][BSTR cols], col index shifted by GOFF with zeroed
// guard zones [0,8) and [520,528) giving free x zero-padding for hblur.
// BSTR = 538: even (float2-aligned rows) and 538 % 32 = 10 -> row bank
// residues {0,10,20,30}: same structure R6 measured at 0 conflicts.
#define BSTR 538
#define GOFF 8
#define VCH(ch,r,xi) uni[((ch)*4 + (r))*BSTR + (xi)]

// order-preserving float->uint encoding so we can use native atomicMax(u32).
// enc(x) > 0 for all reals, so a 0-initialized slot acts as -inf.
__device__ inline unsigned encf(float f) {
    unsigned u = __float_as_uint(f);
    return (u & 0x80000000u) ? ~u : (u | 0x80000000u);
}
__device__ inline float decf(unsigned e) {
    unsigned u = (e & 0x80000000u) ? (e ^ 0x80000000u) : ~e;
    return __uint_as_float(u);
}

__global__ __launch_bounds__(256) void maxred_kernel(
        const float* __restrict__ in, const float* __restrict__ tg,
        const float* __restrict__ mk, unsigned* __restrict__ mx) {
    const float4* in4 = (const float4*)in;
    const float4* tg4 = (const float4*)tg;
    const float4* mk4 = (const float4*)mk;
    long long n4 = NPIX / 4;
    long long idx = (long long)blockIdx.x * blockDim.x + threadIdx.x;
    long long stride = (long long)gridDim.x * blockDim.x;
    float ma = -INFINITY, mb = -INFINITY;   // two independent chains
    for (long long i = idx; i < n4; i += stride) {
        float4 a = in4[i], b = tg4[i], c = mk4[i];
        ma = fmaxf(ma, fmaxf(fmaxf(a.x * c.x, a.y * c.y), fmaxf(a.z * c.z, a.w * c.w)));
        mb = fmaxf(mb, fmaxf(fmaxf(b.x * c.x, b.y * c.y), fmaxf(b.z * c.z, b.w * c.w)));
    }
    float m = fmaxf(ma, mb);
    #pragma unroll
    for (int off = 32; off; off >>= 1) m = fmaxf(m, __shfl_down(m, off, 64));
    __shared__ float smax[4];
    int lane = threadIdx.x & 63, wid = threadIdx.x >> 6;
    if (lane == 0) smax[wid] = m;
    __syncthreads();
    if (threadIdx.x == 0) {
        float r = fmaxf(fmaxf(smax[0], smax[1]), fmaxf(smax[2], smax[3]));
        atomicMax(mx, encf(r));
    }
}

// Band kernel: block = 512 threads = 512 columns, 4 output rows per block.
// (512,3): VGPR cap ~128 -> live set (~50) fits with pipelining slack, no spill.
__global__ __launch_bounds__(512, 3) void ssim_kernel(
        const float* __restrict__ in, const float* __restrict__ tg,
        const float* __restrict__ mk, const float* __restrict__ win,
        const unsigned* __restrict__ mxp, double* __restrict__ sum,
        unsigned* __restrict__ cnt, float* __restrict__ out) {
    __shared__ __align__(16) float uni[24 * BSTR];   // 51648 B -> 3 blocks/CU
    __shared__ float ssum[8];

    int t = threadIdx.x;
    int lane = t & 63, wid = t >> 6;

    // ---- per-wave: separable 1-D gaussian weights -> SGPRs (no LDS, no barrier)
    float rs = 0.f;
    if (lane < 11) {
        #pragma unroll
        for (int j = 0; j < 11; j++) rs += win[lane * 11 + j];
    }
    float wk[11];
    #pragma unroll
    for (int k = 0; k < 11; k++)
        wk[k] = __uint_as_float(__builtin_amdgcn_readfirstlane(
                    __float_as_uint(__shfl(rs, k, 64))));

    // uniform scalar from the max pass (used only in the epilogue)
    float L = decf(*mxp);
    float C3 = 0.5f * (0.03f * L) * (0.03f * L);

    int img = blockIdx.y;
    int y0 = blockIdx.x * 4;               // this band's 4 output rows
    const size_t base = (size_t)img * H * W;
    const float* __restrict__ inb = in + base;
    const float* __restrict__ tgb = tg + base;
    const float* __restrict__ mkb = mk + base;

    // ---- zero the x guard zones (xi in [0,8) and [520,528), 24 rows)
    if (t < 384) {
        int row = t >> 4, g = t & 15;
        int xi = (g < 8) ? g : 512 + g;    // 0..7 or 520..527
        uni[row * BSTR + xi] = 0.f;
    }

    // ---- vertical blur: thread = column x (always in-bounds: no x masking).
    // 14 input rows -> 4 output rows, acc[6][4] = 24 VGPRs, exact 11-tap FMAs.
    {
        int x = t;
        int ybase = y0 - 5;
        float acc[6][4];
        #pragma unroll
        for (int ch = 0; ch < 6; ch++)
            #pragma unroll
            for (int u = 0; u < 4; u++) acc[ch][u] = 0.f;

        if (ybase >= 0 && ybase + 13 < H) {
            // interior band (124 of 128): unconditional coalesced loads
            size_t g = (size_t)ybase * W + x;
            #pragma unroll
            for (int j = 0; j < 14; j++) {
                float iv = inb[g], tv = tgb[g], m = mkb[g];
                g += W;
                float a = iv * m, b = tv * m;
                float v[6] = { m, a, b, a * a, b * b, a * b };
                #pragma unroll
                for (int u = 0; u < 4; u++) {
                    int k = j - u;
                    if (k >= 0 && k < 11) {            // compile-time pruned
                        float w = wk[k];
                        #pragma unroll
                        for (int ch = 0; ch < 6; ch++)
                            acc[ch][u] = fmaf(w, v[ch], acc[ch][u]);
                    }
                }
            }
        } else {
            // y-edge bands (0,1,126,127): clamp + zero the mask channel
            #pragma unroll
            for (int j = 0; j < 14; j++) {
                int y = ybase + j;
                bool yok = (unsigned)y < (unsigned)H;
                size_t g = (size_t)(yok ? y : 0) * W + x;
                float sc = yok ? 1.f : 0.f;
                float iv = inb[g], tv = tgb[g], m = mkb[g] * sc;
                float a = iv * m, b = tv * m;
                float v[6] = { m, a, b, a * a, b * b, a * b };
                #pragma unroll
                for (int u = 0; u < 4; u++) {
                    int k = j - u;
                    if (k >= 0 && k < 11) {
                        float w = wk[k];
                        #pragma unroll
                        for (int ch = 0; ch < 6; ch++)
                            acc[ch][u] = fmaf(w, v[ch], acc[ch][u]);
                    }
                }
            }
        }
        #pragma unroll
        for (int u = 0; u < 4; u++)
            #pragma unroll
            for (int ch = 0; ch < 6; ch++) VCH(ch, u, x + GOFF) = acc[ch][u];
    }

    __syncthreads();   // hblur reads cross wave boundaries

    // ---- horizontal blur + structure map.
    // Mapping (R6's measured-conflict-free pattern): row = lane>>4,
    // col-pair = 32*wid + 2*(lane&15), two halves 256 apart -> 4 px/thread.
    int r = lane >> 4;
    int cbase = 32 * wid + 2 * (lane & 15);
    float lsum = 0.f;
    #pragma unroll
    for (int half = 0; half < 2; half++) {
        int cb = cbase + half * 256;
        float hs[6][2];
        #pragma unroll
        for (int ch = 0; ch < 6; ch++) {
            float Wl[14];
            #pragma unroll
            for (int q = 0; q < 7; q++) {
                float2 v = *(const float2*)&VCH(ch, r, cb - 6 + GOFF + 2 * q);
                Wl[2 * q] = v.x; Wl[2 * q + 1] = v.y;
            }
            #pragma unroll
            for (int u = 0; u < 2; u++) {
                float h = 0.f;
                #pragma unroll
                for (int k = 0; k < 11; k++) h = fmaf(wk[k], Wl[u + 1 + k], h);
                hs[ch][u] = h;
            }
        }
        // structure map, num/den multiplied through by mw^2 (no per-pixel divide)
        #pragma unroll
        for (int u = 0; u < 2; u++) {
            float h1 = hs[1][u], h2 = hs[2][u];
            float mw = hs[0][u] + 1e-8f;
            float mw2 = mw * mw;
            float e12 = 1e-12f * mw2;
            float Xi = fmaxf(fmaf(hs[3][u], mw, -h1 * h1), 0.f) + e12;
            float Xt = fmaxf(fmaf(hs[4][u], mw, -h2 * h2), 0.f) + e12;
            float num = fmaf(hs[5][u], mw, -h1 * h2) + C3 * mw2;
            float den = __builtin_amdgcn_sqrtf(Xi * Xt) + (C3 + 1e-8f) * mw2;
            lsum += num * __builtin_amdgcn_rcpf(den);
        }
    }

    #pragma unroll
    for (int off = 32; off; off >>= 1) lsum += __shfl_down(lsum, off, 64);
    if (lane == 0) ssum[wid] = lsum;
    __syncthreads();                 // final block reduce
    if (t == 0) {
        float tot = 0.f;
        #pragma unroll
        for (int w8 = 0; w8 < 8; w8++) tot += ssum[w8];
        atomicAdd(sum, (double)tot);
        __threadfence();             // sum visible before the counter bump
        unsigned total = gridDim.x * gridDim.y * gridDim.z;
        if (atomicAdd(cnt, 1u) == total - 1u) {
            // fused finalize: last block reads the converged sum (device-scope)
            unsigned long long bits = atomicAdd((unsigned long long*)sum, 0ULL);
            double s = __longlong_as_double((long long)bits);
            out[0] = 1.0f - (float)(s / (double)NPIX);
        }
    }
}

extern "C" void kernel_launch(void* const* d_in, const int* in_sizes, int n_in,
                              void* d_out, int out_size, void* d_ws, size_t ws_size,
                              hipStream_t stream) {
    const float* in  = (const float*)d_in[0];
    const float* tg  = (const float*)d_in[1];
    const float* mk  = (const float*)d_in[2];
    const float* win = (const float*)d_in[3];
    float* out = (float*)d_out;

    double*   dsum = (double*)d_ws;
    unsigned* dmax = (unsigned*)((char*)d_ws + 8);
    unsigned* dcnt = (unsigned*)((char*)d_ws + 12);

    // dsum = 0.0, dmax = 0 (order-encoding floor), dcnt = 0
    hipMemsetAsync(d_ws, 0, 16, stream);
    maxred_kernel<<<2048, 256, 0, stream>>>(in, tg, mk, dmax);
    ssim_kernel<<<dim3(128, 32), 512, 0, stream>>>(in, tg, mk, win, dmax,
                                                   dsum, dcnt, out);
}